// Round 1
// baseline (3759.931 us; speedup 1.0000x reference)
//
#include <hip/hip_runtime.h>
#include <math.h>

#define BATCH 8

// Scatter: one thread per face. For face (i,j,k):
//   dst i receives src j,k ; dst j receives i,k ; dst k receives i,j
//   deg[corner] += 2 per face (each corner appears twice as dst).
__global__ void scatter_kernel(const float* __restrict__ vert,
                               const int*   __restrict__ faces,
                               float* __restrict__ nbr,   // [B][N][3]
                               float* __restrict__ deg,   // [N]
                               int N, int F) {
    int f = blockIdx.x * blockDim.x + threadIdx.x;
    if (f >= F) return;

    int i = faces[3 * f + 0];
    int j = faces[3 * f + 1];
    int k = faces[3 * f + 2];

    atomicAdd(&deg[i], 2.0f);
    atomicAdd(&deg[j], 2.0f);
    atomicAdd(&deg[k], 2.0f);

    int oi = 3 * i, oj = 3 * j, ok = 3 * k;

    #pragma unroll
    for (int b = 0; b < BATCH; ++b) {
        const float* vb = vert + (size_t)b * N * 3;
        float*       nb = nbr  + (size_t)b * N * 3;

        float vi0 = vb[oi + 0], vi1 = vb[oi + 1], vi2 = vb[oi + 2];
        float vj0 = vb[oj + 0], vj1 = vb[oj + 1], vj2 = vb[oj + 2];
        float vk0 = vb[ok + 0], vk1 = vb[ok + 1], vk2 = vb[ok + 2];

        atomicAdd(&nb[oi + 0], vj0 + vk0);
        atomicAdd(&nb[oi + 1], vj1 + vk1);
        atomicAdd(&nb[oi + 2], vj2 + vk2);

        atomicAdd(&nb[oj + 0], vi0 + vk0);
        atomicAdd(&nb[oj + 1], vi1 + vk1);
        atomicAdd(&nb[oj + 2], vi2 + vk2);

        atomicAdd(&nb[ok + 0], vi0 + vj0);
        atomicAdd(&nb[ok + 1], vi1 + vj1);
        atomicAdd(&nb[ok + 2], vi2 + vj2);
    }
}

// Finalize: one thread per (b, v).
// lap_c = nbr[b][v][c] / max(deg[v], 1) - vert[b][v][c]; out = ||lap||_2
__global__ void finalize_kernel(const float* __restrict__ vert,
                                const float* __restrict__ nbr,
                                const float* __restrict__ deg,
                                float* __restrict__ out,
                                int N) {
    int tid = blockIdx.x * blockDim.x + threadIdx.x;
    int total = BATCH * N;
    if (tid >= total) return;

    int b = tid / N;
    int v = tid - b * N;

    float d = fmaxf(deg[v], 1.0f);
    int base = (b * N + v) * 3;

    float l0 = nbr[base + 0] / d - vert[base + 0];
    float l1 = nbr[base + 1] / d - vert[base + 1];
    float l2 = nbr[base + 2] / d - vert[base + 2];

    out[tid] = sqrtf(l0 * l0 + l1 * l1 + l2 * l2);
}

extern "C" void kernel_launch(void* const* d_in, const int* in_sizes, int n_in,
                              void* d_out, int out_size, void* d_ws, size_t ws_size,
                              hipStream_t stream) {
    const float* vert  = (const float*)d_in[0];
    const int*   faces = (const int*)d_in[1];
    float*       out   = (float*)d_out;

    int N = out_size / BATCH;          // 500000
    int F = in_sizes[1] / 3;           // 1000000

    // Workspace layout: nbr_sum [B][N][3] floats, then deg [N] floats.
    float* nbr = (float*)d_ws;
    float* deg = nbr + (size_t)BATCH * N * 3;
    size_t zero_bytes = ((size_t)BATCH * N * 3 + (size_t)N) * sizeof(float);

    hipMemsetAsync(d_ws, 0, zero_bytes, stream);

    int threads = 256;
    int blocks_scatter = (F + threads - 1) / threads;
    scatter_kernel<<<blocks_scatter, threads, 0, stream>>>(vert, faces, nbr, deg, N, F);

    int total = BATCH * N;
    int blocks_fin = (total + threads - 1) / threads;
    finalize_kernel<<<blocks_fin, threads, 0, stream>>>(vert, nbr, deg, out, N);
}

// Round 2
// 1342.840 us; speedup vs baseline: 2.8000x; 2.8000x over previous
//
#include <hip/hip_runtime.h>
#include <math.h>

#define BATCH 8
#define SCAN_T 256
#define SCAN_E 8
#define SCAN_TILE (SCAN_T * SCAN_E)   // 2048 elems per scan block

// ---------------- CSR build ----------------

// cnt[v] += 2 per corner occurrence (matches reference deg)
__global__ void count_kernel(const int* __restrict__ faces, int* __restrict__ cnt, int F) {
    int f = blockIdx.x * blockDim.x + threadIdx.x;
    if (f >= F) return;
    int i = faces[3 * f + 0];
    int j = faces[3 * f + 1];
    int k = faces[3 * f + 2];
    atomicAdd(&cnt[i], 2);
    atomicAdd(&cnt[j], 2);
    atomicAdd(&cnt[k], 2);
}

// Per-block exclusive scan of cnt -> off (block-local), block totals -> bsums
__global__ void scan1_kernel(const int* __restrict__ cnt, int* __restrict__ off,
                             int* __restrict__ bsums, int N) {
    __shared__ int sh[SCAN_T];
    int base = blockIdx.x * SCAN_TILE + threadIdx.x * SCAN_E;
    int vals[SCAN_E];
    int s = 0;
    #pragma unroll
    for (int e = 0; e < SCAN_E; ++e) {
        int v = (base + e < N) ? cnt[base + e] : 0;
        vals[e] = v;
        s += v;
    }
    sh[threadIdx.x] = s;
    __syncthreads();
    for (int d = 1; d < SCAN_T; d <<= 1) {
        int t = (threadIdx.x >= (unsigned)d) ? sh[threadIdx.x - d] : 0;
        __syncthreads();
        sh[threadIdx.x] += t;
        __syncthreads();
    }
    int excl = (threadIdx.x > 0) ? sh[threadIdx.x - 1] : 0;
    if (threadIdx.x == SCAN_T - 1) bsums[blockIdx.x] = sh[SCAN_T - 1];
    #pragma unroll
    for (int e = 0; e < SCAN_E; ++e) {
        if (base + e < N) off[base + e] = excl;
        excl += vals[e];
    }
}

// Exclusive scan of block sums (nb <= SCAN_T expected; serial fallback otherwise)
__global__ void scan2_kernel(int* bsums, int nb) {
    __shared__ int sh[SCAN_T];
    if (nb <= SCAN_T) {
        int v = ((int)threadIdx.x < nb) ? bsums[threadIdx.x] : 0;
        sh[threadIdx.x] = v;
        __syncthreads();
        for (int d = 1; d < SCAN_T; d <<= 1) {
            int t = (threadIdx.x >= (unsigned)d) ? sh[threadIdx.x - d] : 0;
            __syncthreads();
            sh[threadIdx.x] += t;
            __syncthreads();
        }
        int excl = (threadIdx.x > 0) ? sh[threadIdx.x - 1] : 0;
        if ((int)threadIdx.x < nb) bsums[threadIdx.x] = excl;
    } else if (threadIdx.x == 0) {
        int run = 0;
        for (int x = 0; x < nb; ++x) { int t = bsums[x]; bsums[x] = run; run += t; }
    }
}

// Add scanned block offsets
__global__ void scan3_kernel(int* __restrict__ off, const int* __restrict__ bsums, int N) {
    int add = bsums[blockIdx.x];
    if (add == 0) return;
    int base = blockIdx.x * SCAN_TILE + threadIdx.x * SCAN_E;
    #pragma unroll
    for (int e = 0; e < SCAN_E; ++e)
        if (base + e < N) off[base + e] += add;
}

// Fill CSR columns. off is used as the running cursor: after this kernel,
// off[v] = start[v] + cnt[v]  (gather recovers start = off[v] - cnt[v]).
__global__ void fill_kernel(const int* __restrict__ faces, int* __restrict__ off,
                            int* __restrict__ col, int F) {
    int f = blockIdx.x * blockDim.x + threadIdx.x;
    if (f >= F) return;
    int i = faces[3 * f + 0];
    int j = faces[3 * f + 1];
    int k = faces[3 * f + 2];
    int p;
    p = atomicAdd(&off[i], 2); col[p] = j; col[p + 1] = k;
    p = atomicAdd(&off[j], 2); col[p] = i; col[p + 1] = k;
    p = atomicAdd(&off[k], 2); col[p] = i; col[p + 1] = j;
}

// ---------------- vert repack (float3 -> padded float4) ----------------

__global__ void repack_kernel(const float* __restrict__ vert, float4* __restrict__ vs4,
                              int total /* B*N */) {
    int t = blockIdx.x * blockDim.x + threadIdx.x;
    if (t >= total) return;
    size_t b3 = (size_t)t * 3;
    vs4[t] = make_float4(vert[b3], vert[b3 + 1], vert[b3 + 2], 0.0f);
}

// ---------------- gather + finalize (packed float4 path) ----------------

__global__ void gather_packed_kernel(const float4* __restrict__ vs4,
                                     const int* __restrict__ cnt,
                                     const int* __restrict__ off,
                                     const int* __restrict__ col,
                                     float* __restrict__ out, int N) {
    int v = blockIdx.x * blockDim.x + threadIdx.x;
    if (v >= N) return;
    int c = cnt[v];
    int end = off[v];        // post-fill: start + c
    int start = end - c;

    float ax[BATCH], ay[BATCH], az[BATCH];
    #pragma unroll
    for (int b = 0; b < BATCH; ++b) { ax[b] = 0.f; ay[b] = 0.f; az[b] = 0.f; }

    for (int e = start; e < end; ++e) {
        int s = col[e];
        #pragma unroll
        for (int b = 0; b < BATCH; ++b) {
            float4 p = vs4[(size_t)b * N + s];
            ax[b] += p.x; ay[b] += p.y; az[b] += p.z;
        }
    }

    float invd = 1.0f / fmaxf((float)c, 1.0f);
    #pragma unroll
    for (int b = 0; b < BATCH; ++b) {
        float4 q = vs4[(size_t)b * N + v];
        float l0 = ax[b] * invd - q.x;
        float l1 = ay[b] * invd - q.y;
        float l2 = az[b] * invd - q.z;
        out[(size_t)b * N + v] = sqrtf(l0 * l0 + l1 * l1 + l2 * l2);
    }
}

// ---------------- gather + finalize (scalar fallback, no repack) ----------------

__global__ void gather_scalar_kernel(const float* __restrict__ vert,
                                     const int* __restrict__ cnt,
                                     const int* __restrict__ off,
                                     const int* __restrict__ col,
                                     float* __restrict__ out, int N) {
    int v = blockIdx.x * blockDim.x + threadIdx.x;
    if (v >= N) return;
    int c = cnt[v];
    int end = off[v];
    int start = end - c;

    float ax[BATCH], ay[BATCH], az[BATCH];
    #pragma unroll
    for (int b = 0; b < BATCH; ++b) { ax[b] = 0.f; ay[b] = 0.f; az[b] = 0.f; }

    for (int e = start; e < end; ++e) {
        int s = col[e];
        #pragma unroll
        for (int b = 0; b < BATCH; ++b) {
            size_t base = ((size_t)b * N + s) * 3;
            ax[b] += vert[base + 0];
            ay[b] += vert[base + 1];
            az[b] += vert[base + 2];
        }
    }

    float invd = 1.0f / fmaxf((float)c, 1.0f);
    #pragma unroll
    for (int b = 0; b < BATCH; ++b) {
        size_t base = ((size_t)b * N + v) * 3;
        float l0 = ax[b] * invd - vert[base + 0];
        float l1 = ay[b] * invd - vert[base + 1];
        float l2 = az[b] * invd - vert[base + 2];
        out[(size_t)b * N + v] = sqrtf(l0 * l0 + l1 * l1 + l2 * l2);
    }
}

// ---------------- launch ----------------

extern "C" void kernel_launch(void* const* d_in, const int* in_sizes, int n_in,
                              void* d_out, int out_size, void* d_ws, size_t ws_size,
                              hipStream_t stream) {
    const float* vert  = (const float*)d_in[0];
    const int*   faces = (const int*)d_in[1];
    float*       out   = (float*)d_out;

    int N = out_size / BATCH;      // 500000
    int F = in_sizes[1] / 3;       // 1000000
    int E = 6 * F;                 // CSR entries

    // Workspace layout (all offsets 16B-aligned by construction for these sizes):
    //   cnt   [N]  int
    //   off   [N]  int
    //   bsums [1024] int
    //   col   [E]  int
    //   vs4   [B*N] float4   (only if ws_size permits)
    char* ws = (char*)d_ws;
    size_t o_cnt   = 0;
    size_t o_off   = o_cnt + ((size_t)N * 4 + 15 & ~(size_t)15);
    size_t o_bsums = o_off + ((size_t)N * 4 + 15 & ~(size_t)15);
    size_t o_col   = o_bsums + 4096;
    size_t o_vs4   = o_col + (((size_t)E * 4 + 15) & ~(size_t)15);
    size_t need_packed = o_vs4 + (size_t)BATCH * N * sizeof(float4);

    int* cnt   = (int*)(ws + o_cnt);
    int* off   = (int*)(ws + o_off);
    int* bsums = (int*)(ws + o_bsums);
    int* col   = (int*)(ws + o_col);
    float4* vs4 = (float4*)(ws + o_vs4);

    bool packed = (ws_size >= need_packed);

    hipMemsetAsync(cnt, 0, (size_t)N * 4, stream);

    int threads = 256;

    // CSR build
    count_kernel<<<(F + threads - 1) / threads, threads, 0, stream>>>(faces, cnt, F);

    int nb = (N + SCAN_TILE - 1) / SCAN_TILE;   // 245 for N=500000
    scan1_kernel<<<nb, SCAN_T, 0, stream>>>(cnt, off, bsums, N);
    scan2_kernel<<<1, SCAN_T, 0, stream>>>(bsums, nb);
    scan3_kernel<<<nb, SCAN_T, 0, stream>>>(off, bsums, N);
    fill_kernel<<<(F + threads - 1) / threads, threads, 0, stream>>>(faces, off, col, F);

    // Gather + finalize
    if (packed) {
        int total = BATCH * N;
        repack_kernel<<<(total + threads - 1) / threads, threads, 0, stream>>>(vert, vs4, total);
        gather_packed_kernel<<<(N + threads - 1) / threads, threads, 0, stream>>>(
            vs4, cnt, off, col, out, N);
    } else {
        gather_scalar_kernel<<<(N + threads - 1) / threads, threads, 0, stream>>>(
            vert, cnt, off, col, out, N);
    }
}

// Round 3
// 661.532 us; speedup vs baseline: 5.6837x; 2.0299x over previous
//
#include <hip/hip_runtime.h>
#include <math.h>

#define BATCH 8
#define SCAN_T 256
#define SCAN_E 8
#define SCAN_TILE (SCAN_T * SCAN_E)   // 2048 elems per scan block

// ---------------- CSR build ----------------

// cnt[v] += 2 per corner occurrence (matches reference deg)
__global__ void count_kernel(const int* __restrict__ faces, int* __restrict__ cnt, int F) {
    int f = blockIdx.x * blockDim.x + threadIdx.x;
    if (f >= F) return;
    int i = faces[3 * f + 0];
    int j = faces[3 * f + 1];
    int k = faces[3 * f + 2];
    atomicAdd(&cnt[i], 2);
    atomicAdd(&cnt[j], 2);
    atomicAdd(&cnt[k], 2);
}

// Per-block exclusive scan of cnt -> off (block-local), block totals -> bsums
__global__ void scan1_kernel(const int* __restrict__ cnt, int* __restrict__ off,
                             int* __restrict__ bsums, int N) {
    __shared__ int sh[SCAN_T];
    int base = blockIdx.x * SCAN_TILE + threadIdx.x * SCAN_E;
    int vals[SCAN_E];
    int s = 0;
    #pragma unroll
    for (int e = 0; e < SCAN_E; ++e) {
        int v = (base + e < N) ? cnt[base + e] : 0;
        vals[e] = v;
        s += v;
    }
    sh[threadIdx.x] = s;
    __syncthreads();
    for (int d = 1; d < SCAN_T; d <<= 1) {
        int t = (threadIdx.x >= (unsigned)d) ? sh[threadIdx.x - d] : 0;
        __syncthreads();
        sh[threadIdx.x] += t;
        __syncthreads();
    }
    int excl = (threadIdx.x > 0) ? sh[threadIdx.x - 1] : 0;
    if (threadIdx.x == SCAN_T - 1) bsums[blockIdx.x] = sh[SCAN_T - 1];
    #pragma unroll
    for (int e = 0; e < SCAN_E; ++e) {
        if (base + e < N) off[base + e] = excl;
        excl += vals[e];
    }
}

// Exclusive scan of block sums
__global__ void scan2_kernel(int* bsums, int nb) {
    __shared__ int sh[SCAN_T];
    if (nb <= SCAN_T) {
        int v = ((int)threadIdx.x < nb) ? bsums[threadIdx.x] : 0;
        sh[threadIdx.x] = v;
        __syncthreads();
        for (int d = 1; d < SCAN_T; d <<= 1) {
            int t = (threadIdx.x >= (unsigned)d) ? sh[threadIdx.x - d] : 0;
            __syncthreads();
            sh[threadIdx.x] += t;
            __syncthreads();
        }
        int excl = (threadIdx.x > 0) ? sh[threadIdx.x - 1] : 0;
        if ((int)threadIdx.x < nb) bsums[threadIdx.x] = excl;
    } else if (threadIdx.x == 0) {
        int run = 0;
        for (int x = 0; x < nb; ++x) { int t = bsums[x]; bsums[x] = run; run += t; }
    }
}

// Add scanned block offsets
__global__ void scan3_kernel(int* __restrict__ off, const int* __restrict__ bsums, int N) {
    int add = bsums[blockIdx.x];
    if (add == 0) return;
    int base = blockIdx.x * SCAN_TILE + threadIdx.x * SCAN_E;
    #pragma unroll
    for (int e = 0; e < SCAN_E; ++e)
        if (base + e < N) off[base + e] += add;
}

// Fill CSR columns. off becomes the running cursor: post-fill off[v] = start[v] + cnt[v].
__global__ void fill_kernel(const int* __restrict__ faces, int* __restrict__ off,
                            int* __restrict__ col, int F) {
    int f = blockIdx.x * blockDim.x + threadIdx.x;
    if (f >= F) return;
    int i = faces[3 * f + 0];
    int j = faces[3 * f + 1];
    int k = faces[3 * f + 2];
    int p;
    p = atomicAdd(&off[i], 2); col[p] = j; col[p + 1] = k;
    p = atomicAdd(&off[j], 2); col[p] = i; col[p + 1] = k;
    p = atomicAdd(&off[k], 2); col[p] = i; col[p + 1] = j;
}

// ---------------- vert repack: [B][N][3] -> [N][B] float4 (vertex-major) ----------------

__global__ void repack_kernel(const float* __restrict__ vert, float4* __restrict__ vs4,
                              int N) {
    int v = blockIdx.x * blockDim.x + threadIdx.x;
    int b = blockIdx.y;
    if (v >= N) return;
    size_t src = ((size_t)b * N + v) * 3;
    vs4[((size_t)v << 3) + b] = make_float4(vert[src], vert[src + 1], vert[src + 2], 0.0f);
}

// ---------------- gather + finalize: thread per (v, b), b in low 3 bits ----------------
// Lanes b=0..7 of the same v read vs4[s*8 + 0..7] => one contiguous 128B block
// per edge, fully consumed (no line over-fetch).

__global__ void gather_kernel(const float4* __restrict__ vs4,
                              const int* __restrict__ cnt,
                              const int* __restrict__ off,
                              const int* __restrict__ col,
                              float* __restrict__ out, int N) {
    int t = blockIdx.x * blockDim.x + threadIdx.x;
    if (t >= N * BATCH) return;
    int v = t >> 3;
    int b = t & 7;

    int c = cnt[v];          // broadcast across the 8 lanes sharing v
    int end = off[v];        // post-fill: start + c
    int start = end - c;

    float ax = 0.f, ay = 0.f, az = 0.f;
    for (int e = start; e < end; ++e) {
        int s = col[e];                          // broadcast across 8 lanes
        float4 p = vs4[((size_t)s << 3) + b];    // 8 lanes -> contiguous 128B
        ax += p.x; ay += p.y; az += p.z;
    }

    float invd = 1.0f / fmaxf((float)c, 1.0f);
    float4 q = vs4[((size_t)v << 3) + b];
    float l0 = ax * invd - q.x;
    float l1 = ay * invd - q.y;
    float l2 = az * invd - q.z;
    out[(size_t)b * N + v] = sqrtf(l0 * l0 + l1 * l1 + l2 * l2);
}

// ---------------- scalar fallback (no repack buffer) ----------------

__global__ void gather_scalar_kernel(const float* __restrict__ vert,
                                     const int* __restrict__ cnt,
                                     const int* __restrict__ off,
                                     const int* __restrict__ col,
                                     float* __restrict__ out, int N) {
    int v = blockIdx.x * blockDim.x + threadIdx.x;
    if (v >= N) return;
    int c = cnt[v];
    int end = off[v];
    int start = end - c;

    float ax[BATCH], ay[BATCH], az[BATCH];
    #pragma unroll
    for (int b = 0; b < BATCH; ++b) { ax[b] = 0.f; ay[b] = 0.f; az[b] = 0.f; }

    for (int e = start; e < end; ++e) {
        int s = col[e];
        #pragma unroll
        for (int b = 0; b < BATCH; ++b) {
            size_t base = ((size_t)b * N + s) * 3;
            ax[b] += vert[base + 0];
            ay[b] += vert[base + 1];
            az[b] += vert[base + 2];
        }
    }

    float invd = 1.0f / fmaxf((float)c, 1.0f);
    #pragma unroll
    for (int b = 0; b < BATCH; ++b) {
        size_t base = ((size_t)b * N + v) * 3;
        float l0 = ax[b] * invd - vert[base + 0];
        float l1 = ay[b] * invd - vert[base + 1];
        float l2 = az[b] * invd - vert[base + 2];
        out[(size_t)b * N + v] = sqrtf(l0 * l0 + l1 * l1 + l2 * l2);
    }
}

// ---------------- launch ----------------

extern "C" void kernel_launch(void* const* d_in, const int* in_sizes, int n_in,
                              void* d_out, int out_size, void* d_ws, size_t ws_size,
                              hipStream_t stream) {
    const float* vert  = (const float*)d_in[0];
    const int*   faces = (const int*)d_in[1];
    float*       out   = (float*)d_out;

    int N = out_size / BATCH;      // 500000
    int F = in_sizes[1] / 3;       // 1000000
    int E = 6 * F;                 // CSR entries

    // Workspace layout:
    //   cnt [N] int | off [N] int | bsums [1024] int | col [E] int | vs4 [N*B] float4
    char* ws = (char*)d_ws;
    size_t o_cnt   = 0;
    size_t o_off   = o_cnt + (((size_t)N * 4 + 15) & ~(size_t)15);
    size_t o_bsums = o_off + (((size_t)N * 4 + 15) & ~(size_t)15);
    size_t o_col   = o_bsums + 4096;
    size_t o_vs4   = o_col + (((size_t)E * 4 + 127) & ~(size_t)127);
    size_t need_packed = o_vs4 + (size_t)N * BATCH * sizeof(float4);

    int* cnt   = (int*)(ws + o_cnt);
    int* off   = (int*)(ws + o_off);
    int* bsums = (int*)(ws + o_bsums);
    int* col   = (int*)(ws + o_col);
    float4* vs4 = (float4*)(ws + o_vs4);

    bool packed = (ws_size >= need_packed);

    hipMemsetAsync(cnt, 0, (size_t)N * 4, stream);

    int threads = 256;

    // CSR build
    count_kernel<<<(F + threads - 1) / threads, threads, 0, stream>>>(faces, cnt, F);

    int nb = (N + SCAN_TILE - 1) / SCAN_TILE;   // 245 for N=500000
    scan1_kernel<<<nb, SCAN_T, 0, stream>>>(cnt, off, bsums, N);
    scan2_kernel<<<1, SCAN_T, 0, stream>>>(bsums, nb);
    scan3_kernel<<<nb, SCAN_T, 0, stream>>>(off, bsums, N);
    fill_kernel<<<(F + threads - 1) / threads, threads, 0, stream>>>(faces, off, col, F);

    // Gather + finalize
    if (packed) {
        dim3 rgrid((N + threads - 1) / threads, BATCH);
        repack_kernel<<<rgrid, threads, 0, stream>>>(vert, vs4, N);
        int total = N * BATCH;
        gather_kernel<<<(total + threads - 1) / threads, threads, 0, stream>>>(
            vs4, cnt, off, col, out, N);
    } else {
        gather_scalar_kernel<<<(N + threads - 1) / threads, threads, 0, stream>>>(
            vert, cnt, off, col, out, N);
    }
}

// Round 4
// 396.957 us; speedup vs baseline: 9.4719x; 1.6665x over previous
//
#include <hip/hip_runtime.h>
#include <math.h>

#define BATCH 8
#define SCAN_T 256
#define SCAN_E 8
#define SCAN_TILE (SCAN_T * SCAN_E)   // 2048 elems per scan block

// ---------------- CSR build ----------------

// cnt[v] += 2 per corner occurrence; rank[corner] = pre-add value (even).
__global__ void count_kernel(const int* __restrict__ faces, int* __restrict__ cnt,
                             int* __restrict__ rank, int F) {
    int f = blockIdx.x * blockDim.x + threadIdx.x;
    if (f >= F) return;
    int i = faces[3 * f + 0];
    int j = faces[3 * f + 1];
    int k = faces[3 * f + 2];
    rank[3 * f + 0] = atomicAdd(&cnt[i], 2);
    rank[3 * f + 1] = atomicAdd(&cnt[j], 2);
    rank[3 * f + 2] = atomicAdd(&cnt[k], 2);
}

// Per-block exclusive scan of cnt -> off (block-local), block totals -> bsums
__global__ void scan1_kernel(const int* __restrict__ cnt, int* __restrict__ off,
                             int* __restrict__ bsums, int N) {
    __shared__ int sh[SCAN_T];
    int base = blockIdx.x * SCAN_TILE + threadIdx.x * SCAN_E;
    int vals[SCAN_E];
    int s = 0;
    #pragma unroll
    for (int e = 0; e < SCAN_E; ++e) {
        int v = (base + e < N) ? cnt[base + e] : 0;
        vals[e] = v;
        s += v;
    }
    sh[threadIdx.x] = s;
    __syncthreads();
    for (int d = 1; d < SCAN_T; d <<= 1) {
        int t = (threadIdx.x >= (unsigned)d) ? sh[threadIdx.x - d] : 0;
        __syncthreads();
        sh[threadIdx.x] += t;
        __syncthreads();
    }
    int excl = (threadIdx.x > 0) ? sh[threadIdx.x - 1] : 0;
    if (threadIdx.x == SCAN_T - 1) bsums[blockIdx.x] = sh[SCAN_T - 1];
    #pragma unroll
    for (int e = 0; e < SCAN_E; ++e) {
        if (base + e < N) off[base + e] = excl;
        excl += vals[e];
    }
}

// Exclusive scan of block sums
__global__ void scan2_kernel(int* bsums, int nb) {
    __shared__ int sh[SCAN_T];
    if (nb <= SCAN_T) {
        int v = ((int)threadIdx.x < nb) ? bsums[threadIdx.x] : 0;
        sh[threadIdx.x] = v;
        __syncthreads();
        for (int d = 1; d < SCAN_T; d <<= 1) {
            int t = (threadIdx.x >= (unsigned)d) ? sh[threadIdx.x - d] : 0;
            __syncthreads();
            sh[threadIdx.x] += t;
            __syncthreads();
        }
        int excl = (threadIdx.x > 0) ? sh[threadIdx.x - 1] : 0;
        if ((int)threadIdx.x < nb) bsums[threadIdx.x] = excl;
    } else if (threadIdx.x == 0) {
        int run = 0;
        for (int x = 0; x < nb; ++x) { int t = bsums[x]; bsums[x] = run; run += t; }
    }
}

// Add scanned block offsets; off stays the PURE start offsets (fill doesn't mutate).
__global__ void scan3_kernel(int* __restrict__ off, const int* __restrict__ bsums, int N) {
    int add = bsums[blockIdx.x];
    if (add == 0) return;
    int base = blockIdx.x * SCAN_TILE + threadIdx.x * SCAN_E;
    #pragma unroll
    for (int e = 0; e < SCAN_E; ++e)
        if (base + e < N) off[base + e] += add;
}

// Atomic-free fill: position = off[v] + rank (both even) -> aligned int2 store.
__global__ void fill_kernel(const int* __restrict__ faces, const int* __restrict__ off,
                            const int* __restrict__ rank, int* __restrict__ col, int F) {
    int f = blockIdx.x * blockDim.x + threadIdx.x;
    if (f >= F) return;
    int i = faces[3 * f + 0];
    int j = faces[3 * f + 1];
    int k = faces[3 * f + 2];
    int ri = rank[3 * f + 0];
    int rj = rank[3 * f + 1];
    int rk = rank[3 * f + 2];
    int2* c2 = (int2*)col;
    c2[(off[i] + ri) >> 1] = make_int2(j, k);
    c2[(off[j] + rj) >> 1] = make_int2(i, k);
    c2[(off[k] + rk) >> 1] = make_int2(i, j);
}

// ---------------- vert repack: [B][N][3] -> [N][B] float4 (vertex-major) ----------------
// b in low 3 bits: writes fully coalesced (1 KB/wave); reads are 8 coalesced segments.

__global__ void repack_kernel(const float* __restrict__ vert, float4* __restrict__ vs4,
                              int N) {
    int t = blockIdx.x * blockDim.x + threadIdx.x;
    if (t >= N * BATCH) return;
    int v = t >> 3;
    int b = t & 7;
    size_t src = ((size_t)b * N + v) * 3;
    vs4[t] = make_float4(vert[src], vert[src + 1], vert[src + 2], 0.0f);
}

// ---------------- gather + finalize: thread per (v, b), b in low 3 bits ----------------
// Lanes b=0..7 of the same v read vs4[s*8 + 0..7] => contiguous 128B, fully consumed.
// col read as int2: two independent gathers per iter (MLP), counts always even.

__global__ void gather_kernel(const float4* __restrict__ vs4,
                              const int* __restrict__ cnt,
                              const int* __restrict__ off,
                              const int* __restrict__ col,
                              float* __restrict__ out, int N) {
    int t = blockIdx.x * blockDim.x + threadIdx.x;
    if (t >= N * BATCH) return;
    int v = t >> 3;
    int b = t & 7;

    int c = cnt[v];          // broadcast across the 8 lanes sharing v
    int start = off[v];      // pure start offset
    const int2* c2 = (const int2*)col;
    int e0 = start >> 1;
    int e1 = (start + c) >> 1;

    float ax = 0.f, ay = 0.f, az = 0.f;
    for (int e = e0; e < e1; ++e) {
        int2 ss = c2[e];                              // broadcast across 8 lanes
        float4 p = vs4[((size_t)ss.x << 3) + b];      // contiguous 128B across lanes
        float4 q = vs4[((size_t)ss.y << 3) + b];
        ax += p.x + q.x;
        ay += p.y + q.y;
        az += p.z + q.z;
    }

    float invd = 1.0f / fmaxf((float)c, 1.0f);
    float4 self = vs4[((size_t)v << 3) + b];
    float l0 = ax * invd - self.x;
    float l1 = ay * invd - self.y;
    float l2 = az * invd - self.z;
    out[(size_t)b * N + v] = sqrtf(l0 * l0 + l1 * l1 + l2 * l2);
}

// ---------------- scalar fallback (no repack buffer) ----------------

__global__ void gather_scalar_kernel(const float* __restrict__ vert,
                                     const int* __restrict__ cnt,
                                     const int* __restrict__ off,
                                     const int* __restrict__ col,
                                     float* __restrict__ out, int N) {
    int v = blockIdx.x * blockDim.x + threadIdx.x;
    if (v >= N) return;
    int c = cnt[v];
    int start = off[v];
    int end = start + c;

    float ax[BATCH], ay[BATCH], az[BATCH];
    #pragma unroll
    for (int b = 0; b < BATCH; ++b) { ax[b] = 0.f; ay[b] = 0.f; az[b] = 0.f; }

    for (int e = start; e < end; ++e) {
        int s = col[e];
        #pragma unroll
        for (int b = 0; b < BATCH; ++b) {
            size_t base = ((size_t)b * N + s) * 3;
            ax[b] += vert[base + 0];
            ay[b] += vert[base + 1];
            az[b] += vert[base + 2];
        }
    }

    float invd = 1.0f / fmaxf((float)c, 1.0f);
    #pragma unroll
    for (int b = 0; b < BATCH; ++b) {
        size_t base = ((size_t)b * N + v) * 3;
        float l0 = ax[b] * invd - vert[base + 0];
        float l1 = ay[b] * invd - vert[base + 1];
        float l2 = az[b] * invd - vert[base + 2];
        out[(size_t)b * N + v] = sqrtf(l0 * l0 + l1 * l1 + l2 * l2);
    }
}

// ---------------- launch ----------------

extern "C" void kernel_launch(void* const* d_in, const int* in_sizes, int n_in,
                              void* d_out, int out_size, void* d_ws, size_t ws_size,
                              hipStream_t stream) {
    const float* vert  = (const float*)d_in[0];
    const int*   faces = (const int*)d_in[1];
    float*       out   = (float*)d_out;

    int N = out_size / BATCH;      // 500000
    int F = in_sizes[1] / 3;       // 1000000
    int E = 6 * F;                 // CSR entries

    // Workspace layout:
    //   cnt [N] int | off [N] int | bsums [1024] int | col [E] int | vs4 [N*B] float4
    // rank [3F] int ALIASES the first 12 MB of vs4 (dead before repack writes vs4).
    char* ws = (char*)d_ws;
    size_t o_cnt   = 0;
    size_t o_off   = o_cnt + (((size_t)N * 4 + 127) & ~(size_t)127);
    size_t o_bsums = o_off + (((size_t)N * 4 + 127) & ~(size_t)127);
    size_t o_col   = o_bsums + 4096;
    size_t o_vs4   = o_col + (((size_t)E * 4 + 127) & ~(size_t)127);
    size_t need_rank   = o_vs4 + (size_t)3 * F * 4;
    size_t need_packed = o_vs4 + (size_t)N * BATCH * sizeof(float4);

    int* cnt   = (int*)(ws + o_cnt);
    int* off   = (int*)(ws + o_off);
    int* bsums = (int*)(ws + o_bsums);
    int* col   = (int*)(ws + o_col);
    float4* vs4 = (float4*)(ws + o_vs4);
    int* rank  = (int*)(ws + o_vs4);   // alias: rank dead before vs4 is written

    bool packed = (ws_size >= need_packed);
    (void)need_rank;

    hipMemsetAsync(cnt, 0, (size_t)N * 4, stream);

    int threads = 256;

    // CSR build (count also captures per-corner rank; fill is atomic-free)
    count_kernel<<<(F + threads - 1) / threads, threads, 0, stream>>>(faces, cnt, rank, F);

    int nb = (N + SCAN_TILE - 1) / SCAN_TILE;   // 245 for N=500000
    scan1_kernel<<<nb, SCAN_T, 0, stream>>>(cnt, off, bsums, N);
    scan2_kernel<<<1, SCAN_T, 0, stream>>>(bsums, nb);
    scan3_kernel<<<nb, SCAN_T, 0, stream>>>(off, bsums, N);
    fill_kernel<<<(F + threads - 1) / threads, threads, 0, stream>>>(faces, off, rank, col, F);

    // Gather + finalize
    if (packed) {
        int total = N * BATCH;
        repack_kernel<<<(total + threads - 1) / threads, threads, 0, stream>>>(vert, vs4, N);
        gather_kernel<<<(total + threads - 1) / threads, threads, 0, stream>>>(
            vs4, cnt, off, col, out, N);
    } else {
        gather_scalar_kernel<<<(N + threads - 1) / threads, threads, 0, stream>>>(
            vert, cnt, off, col, out, N);
    }
}